// Round 12
// baseline (194.168 us; speedup 1.0000x reference)
//
#include <hip/hip_runtime.h>
#include <hip/hip_bf16.h>

typedef __hip_bfloat16 bf16;
typedef __attribute__((ext_vector_type(8))) short short8;   // 8 bf16 = 4 VGPRs
typedef __attribute__((ext_vector_type(4))) short short4v;  // 4 bf16 = 8 B
typedef __attribute__((ext_vector_type(4))) float float4v;
typedef __attribute__((ext_vector_type(16))) float f32x16;
typedef __attribute__((ext_vector_type(4))) int int4v;

__device__ __forceinline__ float b2f(bf16 v) { return __bfloat162float(v); }
__device__ __forceinline__ bf16  f2b(float v) { return __float2bfloat16(v); }
__device__ __forceinline__ short f2s(float v) { bf16 h = f2b(v); return *reinterpret_cast<short*>(&h); }
__device__ __forceinline__ float s2f(short s) { bf16 h; *reinterpret_cast<short*>(&h) = s; return b2f(h); }
__device__ __forceinline__ short8 ld8(const bf16* p) { return *(const short8*)p; }

// Dtype-flagged input load: f32 != 0 -> buffer is fp32, else bf16.
__device__ __forceinline__ float ldin(const void* p, size_t i, int f32) {
  return f32 ? ((const float*)p)[i] : b2f(((const bf16*)p)[i]);
}

__device__ __forceinline__ float4v mfma16(short8 a, short8 b, float4v c) {
  return __builtin_amdgcn_mfma_f32_16x16x32_bf16(a, b, c, 0, 0, 0);
}
__device__ __forceinline__ f32x16 mfma32(short8 a, short8 b, f32x16 c) {
  return __builtin_amdgcn_mfma_f32_32x32x16_bf16(a, b, c, 0, 0, 0);
}
// 2 f32 -> packed 2x bf16 (low = a). No builtin on gfx950; T12 recipe.
__device__ __forceinline__ int cvtpk(float a, float b) {
  int r; asm("v_cvt_pk_bf16_f32 %0, %1, %2" : "=v"(r) : "v"(a), "v"(b)); return r;
}
// Mutual swap: x' = [x_lo, y_lo], y' = [x_hi, y_hi] (32-lane halves).
__device__ __forceinline__ void plswap(int& x, int& y) {
  asm("v_permlane32_swap_b32 %0, %1" : "+v"(x), "+v"(y));
}

// Async 16B global -> LDS DMA. LDS dest wave-uniform; HW adds lane*16.
__device__ __forceinline__ void gload16(const void* g, void* l) {
  __builtin_amdgcn_global_load_lds((__attribute__((address_space(1))) void*)(void*)g,
                                   (__attribute__((address_space(3))) void*)l, 16, 0, 0);
}

// Per-block dtype self-detection from the first 16 KB of x (fp32 data shows
// bf16 inf/NaN exponent patterns in its halfwords). Replaces the former
// 1-block detect_kernel launch (R11: removing that serialization edge was
// -8 us). Requires blockDim.x == 256; one uniform __syncthreads pair.
__device__ __forceinline__ int self_detect(const void* x, int* sh) {
  const int tid = threadIdx.x;
  if (tid == 0) *sh = 0;
  __syncthreads();
  int local = 0;
  const short8* xv = (const short8*)x;
#pragma unroll
  for (int i = 0; i < 4; i++) {
    const short8 v = xv[tid + i * 256];
#pragma unroll
    for (int j = 0; j < 8; j++)
      if ((((unsigned short)v[j]) & 0x7F80u) == 0x7F80u) local = 1;
  }
  if (local) atomicOr(sh, 1);
  __syncthreads();
  return *sh;
}

// Constants: b=16, c=512, t=1024, 32 groups x 16ch, 8 heads, dh=64.
#define K2SCALE 0.18033688011112042f   // 0.125 * log2(e), folded into Q
#define TSTRIDE 72                     // 36 dwords == 4 mod 32: 2-way free

// ---------------------------------------------------------------------------
// Kernel 0+1a fused: weight/bias bf16 conversion AND GroupNorm stats in one
// launch. Conversion loads VECTORIZED (float4/short4 per thread, was 4
// scalar). blk<768: w_qkv | <1024: w_proj | <1026: b_qkv | 1026: b_proj |
// >=1027: stats.
// ---------------------------------------------------------------------------
__global__ __launch_bounds__(256) void pre_kernel(const void* __restrict__ s1, bf16* __restrict__ d1,
                                                  const void* __restrict__ s2, bf16* __restrict__ d2,
                                                  const void* __restrict__ s3, bf16* __restrict__ d3,
                                                  const void* __restrict__ s4, bf16* __restrict__ d4,
                                                  const void* __restrict__ x,
                                                  float2* __restrict__ stats) {
  const int blk = blockIdx.x;
  const int tid = threadIdx.x;
  __shared__ int fl;
  __shared__ float rs[4], rss[4];
  const int f32 = self_detect(x, &fl);

  if (blk < 1027) {                      // ---- conversion part ----
    const void* src; bf16* dst; int base, n;
    if (blk < 768)       { src = s1; dst = d1; base = blk;        n = 786432; }
    else if (blk < 1024) { src = s2; dst = d2; base = blk - 768;  n = 262144; }
    else if (blk < 1026) { src = s3; dst = d3; base = blk - 1024; n = 1536;   }
    else                 { src = s4; dst = d4; base = 0;          n = 512;    }
    const int i0 = (base * 256 + tid) * 4;
    if (i0 + 3 < n) {                    // full vector (always for w/b blocks)
      short4v pk;
      if (f32) {
        const float4v v = *(const float4v*)((const float*)src + i0);
#pragma unroll
        for (int j = 0; j < 4; j++) pk[j] = f2s(v[j]);
      } else {
        pk = *(const short4v*)((const bf16*)src + i0);
      }
      *(short4v*)(dst + i0) = pk;
    } else {
      for (int j = 0; j < 4; j++) {
        int i = i0 + j;
        if (i < n) dst[i] = f2b(ldin(src, i, f32));
      }
    }
    return;
  }

  // ---- GroupNorm stats part: one block per (b,g) ----
  const int bg = blk - 1027;
  const int GSZ = 16 * 1024;
  const size_t base = (size_t)bg * GSZ;

  float s = 0.f, ss = 0.f;
  if (f32) {
    const float4v* xp = (const float4v*)((const float*)x + base) + tid;
#pragma unroll
    for (int i = 0; i < 16; i++) {
      float4v v = xp[i * 256];
#pragma unroll
      for (int j = 0; j < 4; j++) { s += v[j]; ss += v[j] * v[j]; }
    }
  } else {
    const short8* xp = (const short8*)((const bf16*)x + base) + tid;
#pragma unroll
    for (int i = 0; i < 8; i++) {
      short8 v = xp[i * 256];
#pragma unroll
      for (int j = 0; j < 8; j++) { float f = s2f(v[j]); s += f; ss += f * f; }
    }
  }
  for (int off = 32; off > 0; off >>= 1) {
    s  += __shfl_down(s, off);
    ss += __shfl_down(ss, off);
  }
  const int wave = tid >> 6, lane = tid & 63;
  if (lane == 0) { rs[wave] = s; rss[wave] = ss; }
  __syncthreads();
  if (tid == 0) {
    s  = rs[0] + rs[1] + rs[2] + rs[3];
    ss = rss[0] + rss[1] + rss[2] + rss[3];
    const float mean = s * (1.f / GSZ);
    const float var  = ss * (1.f / GSZ) - mean * mean;
    stats[bg] = make_float2(mean, rsqrtf(var + 1e-5f));
  }
}

// ---------------------------------------------------------------------------
// Kernel 1b: GroupNorm apply + [c][t] -> [t][c] transpose via LDS.
// R12: tile 64t -> 32t: grid (32,16,4) = 2048 blocks = 8/CU (was 4/CU),
// LDS ~10 KB; write phase via short8 (16B) stores, 2/thread (was 16x 4B).
// Both memory-bound levers: more resident waves + fewer store instrs.
// ---------------------------------------------------------------------------
__global__ __launch_bounds__(256) void gn_apply_kernel(const void* __restrict__ x,
                                                       const void* __restrict__ gsc,
                                                       const void* __restrict__ gbi,
                                                       const float2* __restrict__ stats,
                                                       bf16* __restrict__ xn) {
  const int b = blockIdx.y;
  const int t0 = blockIdx.x * 32;
  const int cs = blockIdx.z * 128;
  const int tid = threadIdx.x;

  __shared__ int fl;
  __shared__ float Aa[128], Bb[128];
  __shared__ short T[32][136];           // row stride 136 shorts
  const int f32 = self_detect(x, &fl);

  if (tid < 128) {
    const int c = cs + tid;
    const float2 st = stats[b * 32 + (c >> 4)];
    const float sc = ldin(gsc, c, f32), bi = ldin(gbi, c, f32);
    Aa[tid] = st.y * sc;
    Bb[tid] = bi - st.x * st.y * sc;
  }
  __syncthreads();

  const int row = tid >> 3;            // c sub-index (0..31), + step*32
  const int t4 = (tid & 7) * 4;        // 4 consecutive t per thread
  if (f32) {
    const float* xb = (const float*)x + ((size_t)(b * 512 + cs)) * 1024 + t0 + t4;
#pragma unroll
    for (int st = 0; st < 4; st++) {
      const int c = row + st * 32;
      const float4v v = *(const float4v*)(xb + (size_t)c * 1024);
      const float aa = Aa[c], bb = Bb[c];
#pragma unroll
      for (int j = 0; j < 4; j++) T[t4 + j][c] = f2s(v[j] * aa + bb);
    }
  } else {
    const bf16* xb = (const bf16*)x + ((size_t)(b * 512 + cs)) * 1024 + t0 + t4;
#pragma unroll
    for (int st = 0; st < 4; st++) {
      const int c = row + st * 32;
      const short4v v = *(const short4v*)(xb + (size_t)c * 1024);
      const float aa = Aa[c], bb = Bb[c];
#pragma unroll
      for (int j = 0; j < 4; j++) T[t4 + j][c] = f2s(s2f(v[j]) * aa + bb);
    }
  }
  __syncthreads();

  // write: 32t x 128c = 512 short8 chunks; 2 per thread, fully coalesced.
#pragma unroll
  for (int j = 0; j < 2; j++) {
    const int ci = tid + j * 256;        // chunk 0..511
    const int t2 = ci >> 4;              // 0..31
    const int c8 = (ci & 15) * 8;        // 0..120
    const short8 v = *(const short8*)&T[t2][c8];
    *(short8*)&xn[((size_t)(b * 1024 + t0 + t2)) * 512 + cs + c8] = v;
  }
}

// ---------------------------------------------------------------------------
// Kernel 2: QKV projection — 128x128 tile, 4 waves, BK=32 (R8 config).
// R9 lesson: widening to 256N shrank the grid to 768 blocks -> ~1 block/CU
// resident, latency-starved. This family wants grid DEPTH (1536 blocks,
// 6/CU queued), not arithmetic intensity.
// 1-barrier-per-iter dbuf gload16 staging; epilogue LDS-transposed.
// ---------------------------------------------------------------------------
__global__ __launch_bounds__(256) void qkv_kernel(const bf16* __restrict__ Wb,
                                                  const bf16* __restrict__ biasb,
                                                  const bf16* __restrict__ xn,
                                                  bf16* __restrict__ Qt,
                                                  bf16* __restrict__ Kt,
                                                  bf16* __restrict__ Vb) {
  const int bat = blockIdx.z;
  const int M0 = blockIdx.y * 128;       // o
  const int N0 = blockIdx.x * 128;       // t
  __shared__ short smem[18432];          // dbuf 2x(A4096|B4096)=16384 | Tt union

  const int tid = threadIdx.x;
  const int w = tid >> 6, lane = tid & 63;
  const int col = lane & 15, g = lane >> 4;
  const int wm = (w & 1) * 64, wn = (w >> 1) * 64;

  float4v acc[4][4];
#pragma unroll
  for (int i = 0; i < 4; i++)
#pragma unroll
    for (int j = 0; j < 4; j++) acc[i][j] = (float4v)(0.f);

  // staging map: tile = 128 rows x 32 k = 512 granules (16B); linear.
  int srco[2], dstb[2];
#pragma unroll
  for (int i = 0; i < 2; i++) {
    const int Gb = i * 256 + w * 64;          // wave-uniform granule base
    dstb[i] = Gb * 8;                         // LDS shorts (lane adds 16B)
    const int G = Gb + lane;
    srco[i] = (G >> 2) * 512 + (G & 3) * 8;   // row*(K=512) + col granule
  }
  const bf16* Ab  = Wb + (size_t)M0 * 512;
  const bf16* Bb2 = xn + ((size_t)bat * 1024 + N0) * 512;

  // preload k=0 into buf 0
#pragma unroll
  for (int i = 0; i < 2; i++) {
    gload16(Ab + srco[i],  &smem[dstb[i]]);
    gload16(Bb2 + srco[i], &smem[4096 + dstb[i]]);
  }
  __syncthreads();

  for (int it = 0; it < 16; ++it) {
    const int pb = it & 1;
    if (it < 15) {                       // prefetch next tile (async)
      const int kn = it * 32 + 32;
      const int nb = (1 - pb) * 8192;
#pragma unroll
      for (int i = 0; i < 2; i++) {
        gload16(Ab + kn + srco[i],  &smem[nb + dstb[i]]);
        gload16(Bb2 + kn + srco[i], &smem[nb + 4096 + dstb[i]]);
      }
    }
    const short* Ap = &smem[pb * 8192];
    const short* Bp = Ap + 4096;
    short8 af[4], bf4[4];
#pragma unroll
    for (int mt = 0; mt < 4; mt++) af[mt] = *(const short8*)&Ap[(wm + mt * 16 + col) * 32 + g * 8];
#pragma unroll
    for (int nt = 0; nt < 4; nt++) bf4[nt] = *(const short8*)&Bp[(wn + nt * 16 + col) * 32 + g * 8];
#pragma unroll
    for (int mt = 0; mt < 4; mt++)
#pragma unroll
      for (int nt = 0; nt < 4; nt++) acc[mt][nt] = mfma16(af[mt], bf4[nt], acc[mt][nt]);
    __syncthreads();                     // reads done + next DMA drained at use
  }

  // ---- epilogue ----
  const int sec = (M0 + wm) >> 6;
  const int h = sec / 3, kind = sec % 3; // 0=Q 1=K 2=V
  const size_t bh = (size_t)bat * 8 + h;
  const float qs = (kind == 0) ? K2SCALE : 1.f;
  short* Tw = smem + w * 4608;

  float bv[4][4];
#pragma unroll
  for (int mt = 0; mt < 4; mt++)
#pragma unroll
    for (int r = 0; r < 4; r++) bv[mt][r] = b2f(biasb[M0 + wm + mt * 16 + g * 4 + r]);

  if (kind == 2) {                       // V -> [c][t]
#pragma unroll
    for (int mt = 0; mt < 4; mt++)
#pragma unroll
      for (int nt = 0; nt < 4; nt++)
#pragma unroll
        for (int r = 0; r < 4; r++) {
          const int lo = mt * 16 + g * 4 + r;
          const int lt = nt * 16 + col;
          Tw[lo * TSTRIDE + lt] = f2s(acc[mt][nt][r] + bv[mt][r]);
        }
#pragma unroll
    for (int j = 0; j < 8; j++) {
      const int lo = j * 8 + (lane >> 3);
      const int gr = lane & 7;
      short8 v = *(const short8*)&Tw[lo * TSTRIDE + gr * 8];
      *(short8*)(Vb + (bh * 64 + lo) * 1024 + N0 + wn + gr * 8) = v;
    }
  } else {                               // Q/K -> [t][c]
#pragma unroll
    for (int mt = 0; mt < 4; mt++)
#pragma unroll
      for (int nt = 0; nt < 4; nt++) {
        short4v pk;
#pragma unroll
        for (int r = 0; r < 4; r++) pk[r] = f2s((acc[mt][nt][r] + bv[mt][r]) * qs);
        *(short4v*)&Tw[(nt * 16 + col) * TSTRIDE + mt * 16 + g * 4] = pk;
      }
    bf16* dst = (kind == 0) ? Qt : Kt;
#pragma unroll
    for (int j = 0; j < 8; j++) {
      const int tl = j * 8 + (lane >> 3), c8 = (lane & 7) * 8;
      short8 v = *(const short8*)&Tw[tl * TSTRIDE + c8];
      *(short8*)(dst + (bh * 1024 + N0 + wn + tl) * 64 + c8) = v;
    }
  }
}

// ---------------------------------------------------------------------------
// Kernel 3: flash attention — R3 core (plateau of this family per R4-R7
// ablations) + S-init via persistent zero-register C operand (R10: 45.4 ->
// 44.3, MfmaUtil 29 -> 31). QBLK=64/wave, KVBLK=64, dbuf K/V (32KB),
// 1 barrier/iter, grid (128,4). Fragment-major LDS (conflict-free via
// per-lane global src permute), T12 in-reg P (cvt_pk + permlane32_swap),
// raw exp2.
// ---------------------------------------------------------------------------
__global__ __launch_bounds__(256, 2) void attn_kernel(const bf16* __restrict__ Qt,
                                                      const bf16* __restrict__ Kt,
                                                      const bf16* __restrict__ Vb,
                                                      bf16* __restrict__ xattn) {
  const int bh = blockIdx.x;             // XCD affinity dim
  const int t0 = blockIdx.y * 256;
  const int b = bh >> 3, h = bh & 7;
  const int tid = threadIdx.x;
  const int w = tid >> 6, lane = tid & 63;
  const int qv = lane & 31, hh = lane >> 5;
  const int q0 = t0 + w * 64;

  __shared__ short Ks[8192];             // 16 KB: dbuf 2 x 4096 shorts
  __shared__ short Vs[8192];             // 16 KB

  const bf16* kbase = Kt + (size_t)bh * 65536;   // [t][c]
  const bf16* vbase = Vb + (size_t)bh * 65536;   // [c][t]

  // staging: granule G = w*128 + i*64 + lane -> (a,ks,qvs,hhs)
  int ksrc[2], vsrc[2];
  const int ldst0 = w * 1024, ldst1 = w * 1024 + 512;   // shorts in buffer
#pragma unroll
  for (int i = 0; i < 2; i++) {
    const int G = w * 128 + i * 64 + lane;
    const int a = G >> 8, ks = (G >> 6) & 3, qvs = (G >> 1) & 31, hhs = G & 1;
    const int co = (ks * 2 + hhs) * 8;          // channel offset (shorts)
    ksrc[i] = (a * 32 + qvs) * 64 + co;         // K row stride 64
    vsrc[i] = (a * 32 + qvs) * 1024 + co;       // V row stride 1024
  }
  const int rb = (qv * 2 + hh) * 8;             // lane-const read offset

  // Q frags (B-operand): lane q=qv, k = 16*ks + 8*hh + i. 32 VGPRs.
  short8 qb[2][4];
#pragma unroll
  for (int qt = 0; qt < 2; qt++)
#pragma unroll
    for (int ks = 0; ks < 4; ks++)
      qb[qt][ks] = ld8(Qt + ((size_t)bh * 1024 + q0 + qt * 32 + qv) * 64 + ks * 16 + hh * 8);

  f32x16 O[2][2];                        // [q-tile][c-half]
#pragma unroll
  for (int qt = 0; qt < 2; qt++)
#pragma unroll
    for (int o = 0; o < 2; o++) O[qt][o] = (f32x16)(0.f);
  float l[2] = {0.f, 0.f};
  short8 pa[2][4];                       // P A-frags per q-tile
  const f32x16 FZ = (f32x16)(0.f);       // persistent zero C-operand

  // preload tile 0 into buf 0
  gload16(kbase + ksrc[0], &Ks[ldst0]);
  gload16(kbase + ksrc[1], &Ks[ldst1]);
  gload16(vbase + vsrc[0], &Vs[ldst0]);
  gload16(vbase + vsrc[1], &Vs[ldst1]);
  __syncthreads();

// exp2 + row-sum + pack S (kv tile a) into pa[qt][2a], pa[qt][2a+1]
#define SMAX(S, qt, a)                                                          \
  {                                                                             \
    _Pragma("unroll")                                                           \
    for (int j = 0; j < 16; j++) S[j] = __builtin_amdgcn_exp2f(S[j]);           \
    l[qt] += (((S[0] + S[1]) + (S[2] + S[3])) + ((S[4] + S[5]) + (S[6] + S[7])))\
       + (((S[8] + S[9]) + (S[10] + S[11])) + ((S[12] + S[13]) + (S[14] + S[15]))); \
    _Pragma("unroll")                                                           \
    for (int kp = 0; kp < 2; kp++) {                                            \
      int X  = cvtpk(S[8 * kp + 0], S[8 * kp + 1]);                             \
      int Y  = cvtpk(S[8 * kp + 4], S[8 * kp + 5]);                             \
      int X2 = cvtpk(S[8 * kp + 2], S[8 * kp + 3]);                             \
      int Y2 = cvtpk(S[8 * kp + 6], S[8 * kp + 7]);                             \
      plswap(X, Y);                                                             \
      plswap(X2, Y2);                                                           \
      const int4v wv = {X, X2, Y, Y2};                                          \
      pa[qt][(a) * 2 + kp] = __builtin_bit_cast(short8, wv);                    \
    }                                                                           \
  }

#pragma unroll 2
  for (int it = 0; it < 16; ++it) {
    const int cur = (it & 1) * 4096;
    const int nxt = 4096 - cur;
    // ---- issue DMA for tile it+1 into the other buffer ----
    if (it < 15) {
      gload16(kbase + (it + 1) * 4096 + ksrc[0], &Ks[nxt + ldst0]);
      gload16(kbase + (it + 1) * 4096 + ksrc[1], &Ks[nxt + ldst1]);
      gload16(vbase + (it + 1) * 64 + vsrc[0],   &Vs[nxt + ldst0]);
      gload16(vbase + (it + 1) * 64 + vsrc[1],   &Vs[nxt + ldst1]);
    }
    // ---- QK + softmax (kf shared across both q-tiles) ----
#pragma unroll
    for (int a = 0; a < 2; a++) {
      short8 kf[4];
#pragma unroll
      for (int ks = 0; ks < 4; ks++)
        kf[ks] = *(const short8*)&Ks[cur + (a * 4 + ks) * 512 + rb];
#pragma unroll
      for (int qt = 0; qt < 2; qt++) {
        f32x16 S = mfma32(kf[0], qb[qt][0], FZ);   // init via MFMA (D != C)
#pragma unroll
        for (int ks = 1; ks < 4; ks++) S = mfma32(kf[ks], qb[qt][ks], S);
        SMAX(S, qt, a);
      }
    }
    // ---- PV (vf shared across both q-tiles) ----
#pragma unroll
    for (int o = 0; o < 2; o++) {
      short8 vf[4];
#pragma unroll
      for (int ks = 0; ks < 4; ks++)
        vf[ks] = *(const short8*)&Vs[cur + (o * 4 + ks) * 512 + rb];
#pragma unroll
      for (int qt = 0; qt < 2; qt++)
#pragma unroll
        for (int ks = 0; ks < 4; ks++)
          O[qt][o] = mfma32(pa[qt][ks], vf[ks], O[qt][o]);
    }
    __syncthreads();                     // reads done; next-buf DMA drained
  }
#undef SMAX

  // ---- epilogue: cross-half row-sum, normalize, direct stores ----
#pragma unroll
  for (int qt = 0; qt < 2; qt++) {
    float lt = l[qt] + __shfl_xor(l[qt], 32);
    const float inv = 1.f / lt;
    float* lf = (float*)Ks + w * 64 + qt * 32;  // Ks dead; disjoint per wave
    lf[qv] = inv;                               // both halves write same value

    bf16* ob = xattn + ((size_t)b * 1024 + q0 + qt * 32 + 4 * hh) * 512 + h * 64 + qv;
#pragma unroll
    for (int r = 0; r < 16; r++) {
      const int qoff = (r & 3) + 8 * (r >> 2);
      const float iv = lf[qoff + 4 * hh];       // same addr across half
      ob[(size_t)qoff * 512]      = f2b(O[qt][0][r] * iv);
      ob[(size_t)qoff * 512 + 32] = f2b(O[qt][1][r] * iv);
    }
  }
}

// ---------------------------------------------------------------------------
// Kernel 4: proj GEMM, same BK=32 dbuf one-barrier staging.
// out = Wp*xattn + bias + x; epilogue transposed, full-line stores.
// Residual loads vectorized (float4 x2 / short8). Dtype via self_detect
// (res == x, so the 16 KB probe is data this kernel reads anyway).
// ---------------------------------------------------------------------------
__global__ __launch_bounds__(256) void proj_kernel(const bf16* __restrict__ Wp,
                                                   const bf16* __restrict__ biasb,
                                                   const bf16* __restrict__ xattn,
                                                   const void* __restrict__ res,
                                                   void* __restrict__ out) {
  const int bat = blockIdx.z;
  const int M0 = blockIdx.y * 128;
  const int N0 = blockIdx.x * 128;
  __shared__ short smem[18432];
  __shared__ int fl;
  const int f32 = self_detect(res, &fl);

  const int tid = threadIdx.x;
  const int w = tid >> 6, lane = tid & 63;
  const int col = lane & 15, g = lane >> 4;
  const int wm = (w & 1) * 64, wn = (w >> 1) * 64;

  float4v acc[4][4];
#pragma unroll
  for (int i = 0; i < 4; i++)
#pragma unroll
    for (int j = 0; j < 4; j++) acc[i][j] = (float4v)(0.f);

  int srco[2], dstb[2];
#pragma unroll
  for (int i = 0; i < 2; i++) {
    const int Gb = i * 256 + w * 64;
    dstb[i] = Gb * 8;
    const int G = Gb + lane;
    srco[i] = (G >> 2) * 512 + (G & 3) * 8;
  }
  const bf16* Ab  = Wp + (size_t)M0 * 512;
  const bf16* Bb2 = xattn + ((size_t)bat * 1024 + N0) * 512;

#pragma unroll
  for (int i = 0; i < 2; i++) {
    gload16(Ab + srco[i],  &smem[dstb[i]]);
    gload16(Bb2 + srco[i], &smem[4096 + dstb[i]]);
  }
  __syncthreads();

  for (int it = 0; it < 16; ++it) {
    const int pb = it & 1;
    if (it < 15) {
      const int kn = it * 32 + 32;
      const int nb = (1 - pb) * 8192;
#pragma unroll
      for (int i = 0; i < 2; i++) {
        gload16(Ab + kn + srco[i],  &smem[nb + dstb[i]]);
        gload16(Bb2 + kn + srco[i], &smem[nb + 4096 + dstb[i]]);
      }
    }
    const short* Ap = &smem[pb * 8192];
    const short* Bp = Ap + 4096;
    short8 af[4], bf4[4];
#pragma unroll
    for (int mt = 0; mt < 4; mt++) af[mt] = *(const short8*)&Ap[(wm + mt * 16 + col) * 32 + g * 8];
#pragma unroll
    for (int nt = 0; nt < 4; nt++) bf4[nt] = *(const short8*)&Bp[(wn + nt * 16 + col) * 32 + g * 8];
#pragma unroll
    for (int mt = 0; mt < 4; mt++)
#pragma unroll
      for (int nt = 0; nt < 4; nt++) acc[mt][nt] = mfma16(af[mt], bf4[nt], acc[mt][nt]);
    __syncthreads();
  }

  short* Tw = smem + w * 4608;
  float bv[4][4];
#pragma unroll
  for (int mt = 0; mt < 4; mt++)
#pragma unroll
    for (int r = 0; r < 4; r++) bv[mt][r] = b2f(biasb[M0 + wm + mt * 16 + g * 4 + r]);

#pragma unroll
  for (int mt = 0; mt < 4; mt++)
#pragma unroll
    for (int nt = 0; nt < 4; nt++)
#pragma unroll
      for (int r = 0; r < 4; r++) {
        const int lo = mt * 16 + g * 4 + r;
        const int lt = nt * 16 + col;
        Tw[lo * TSTRIDE + lt] = f2s(acc[mt][nt][r] + bv[mt][r]);
      }
#pragma unroll
  for (int j = 0; j < 8; j++) {
    const int lo = j * 8 + (lane >> 3);
    const int gr = lane & 7;
    short8 v = *(const short8*)&Tw[lo * TSTRIDE + gr * 8];
    const int o = M0 + wm + lo;
    const size_t ci = ((size_t)bat * 512 + o) * 1024 + N0 + wn + gr * 8;
    if (f32) {
      const float4v r0 = *(const float4v*)((const float*)res + ci);
      const float4v r1 = *(const float4v*)((const float*)res + ci + 4);
      float4v o0, o1;
#pragma unroll
      for (int e = 0; e < 4; e++) o0[e] = s2f(v[e]) + r0[e];
#pragma unroll
      for (int e = 0; e < 4; e++) o1[e] = s2f(v[e + 4]) + r1[e];
      *(float4v*)((float*)out + ci) = o0;
      *(float4v*)((float*)out + ci + 4) = o1;
    } else {
      const short8 rv = *(const short8*)((const bf16*)res + ci);
      short8 ov;
#pragma unroll
      for (int e = 0; e < 8; e++)
        ov[e] = f2s(s2f(v[e]) + s2f(rv[e]));
      *(short8*)((bf16*)out + ci) = ov;
    }
  }
}

// ---------------------------------------------------------------------------
extern "C" void kernel_launch(void* const* d_in, const int* in_sizes, int n_in,
                              void* d_out, int out_size, void* d_ws, size_t ws_size,
                              hipStream_t stream) {
  const void* x      = d_in[0];
  const void* gsc    = d_in[1];
  const void* gbi    = d_in[2];
  const void* w_qkv  = d_in[3];
  const void* b_qkv  = d_in[4];
  const void* w_proj = d_in[5];
  const void* b_proj = d_in[6];

  char* p = (char*)d_ws;
  float2* stats = (float2*)p;              p += 1024 * sizeof(float2);
  bf16*   xn    = (bf16*)p;                p += (size_t)16 * 1024 * 512 * 2;
  bf16*   Qt    = (bf16*)p;                p += (size_t)128 * 1024 * 64 * 2;
  bf16*   Kt    = (bf16*)p;                p += (size_t)128 * 1024 * 64 * 2;
  bf16*   Vb    = (bf16*)p;                p += (size_t)128 * 64 * 1024 * 2;
  bf16*   Wqb   = (bf16*)p;                p += (size_t)1536 * 512 * 2;
  bf16*   Wpb   = (bf16*)p;                p += (size_t)512 * 512 * 2;
  bf16*   Bqb   = (bf16*)p;                p += (size_t)1536 * 2;
  bf16*   Bpb   = (bf16*)p;                p += (size_t)512 * 2;
  bf16*   xattn = (bf16*)p;

  pre_kernel<<<1539, 256, 0, stream>>>(w_qkv, Wqb, w_proj, Wpb,
                                       b_qkv, Bqb, b_proj, Bpb,
                                       x, stats);
  gn_apply_kernel<<<dim3(32, 16, 4), 256, 0, stream>>>(x, gsc, gbi, stats, xn);
  qkv_kernel<<<dim3(8, 12, 16), 256, 0, stream>>>(Wqb, Bqb, xn, Qt, Kt, Vb);
  attn_kernel<<<dim3(128, 4), 256, 0, stream>>>(Qt, Kt, Vb, xattn);
  proj_kernel<<<dim3(8, 4, 16), 256, 0, stream>>>(Wpb, Bpb, xattn, x, d_out);
}

// Round 14
// 191.311 us; speedup vs baseline: 1.0149x; 1.0149x over previous
//
#include <hip/hip_runtime.h>
#include <hip/hip_bf16.h>

typedef __hip_bfloat16 bf16;
typedef __attribute__((ext_vector_type(8))) short short8;   // 8 bf16 = 4 VGPRs
typedef __attribute__((ext_vector_type(4))) short short4v;  // 4 bf16 = 8 B
typedef __attribute__((ext_vector_type(4))) float float4v;
typedef __attribute__((ext_vector_type(16))) float f32x16;
typedef __attribute__((ext_vector_type(4))) int int4v;

__device__ __forceinline__ float b2f(bf16 v) { return __bfloat162float(v); }
__device__ __forceinline__ bf16  f2b(float v) { return __float2bfloat16(v); }
__device__ __forceinline__ short f2s(float v) { bf16 h = f2b(v); return *reinterpret_cast<short*>(&h); }
__device__ __forceinline__ float s2f(short s) { bf16 h; *reinterpret_cast<short*>(&h) = s; return b2f(h); }
__device__ __forceinline__ short8 ld8(const bf16* p) { return *(const short8*)p; }

// Dtype-flagged input load: f32 != 0 -> buffer is fp32, else bf16.
__device__ __forceinline__ float ldin(const void* p, size_t i, int f32) {
  return f32 ? ((const float*)p)[i] : b2f(((const bf16*)p)[i]);
}

__device__ __forceinline__ float4v mfma16(short8 a, short8 b, float4v c) {
  return __builtin_amdgcn_mfma_f32_16x16x32_bf16(a, b, c, 0, 0, 0);
}
__device__ __forceinline__ f32x16 mfma32(short8 a, short8 b, f32x16 c) {
  return __builtin_amdgcn_mfma_f32_32x32x16_bf16(a, b, c, 0, 0, 0);
}
// 2 f32 -> packed 2x bf16 (low = a). No builtin on gfx950; T12 recipe.
__device__ __forceinline__ int cvtpk(float a, float b) {
  int r; asm("v_cvt_pk_bf16_f32 %0, %1, %2" : "=v"(r) : "v"(a), "v"(b)); return r;
}
// Mutual swap: x' = [x_lo, y_lo], y' = [x_hi, y_hi] (32-lane halves).
__device__ __forceinline__ void plswap(int& x, int& y) {
  asm("v_permlane32_swap_b32 %0, %1" : "+v"(x), "+v"(y));
}

// Async 16B global -> LDS DMA. LDS dest wave-uniform; HW adds lane*16.
__device__ __forceinline__ void gload16(const void* g, void* l) {
  __builtin_amdgcn_global_load_lds((__attribute__((address_space(1))) void*)(void*)g,
                                   (__attribute__((address_space(3))) void*)l, 16, 0, 0);
}

// Per-block dtype self-detection from the first 16 KB of x (fp32 data shows
// bf16 inf/NaN exponent patterns in its halfwords). Replaces the former
// 1-block detect_kernel launch (R11: removing that serialization edge was
// -8 us). Works for any blockDim that divides 1024; uniform barriers.
__device__ __forceinline__ int self_detect(const void* x, int* sh) {
  const int tid = threadIdx.x;
  if (tid == 0) *sh = 0;
  __syncthreads();
  int local = 0;
  const short8* xv = (const short8*)x;
  for (int idx = tid; idx < 1024; idx += blockDim.x) {
    const short8 v = xv[idx];
#pragma unroll
    for (int j = 0; j < 8; j++)
      if ((((unsigned short)v[j]) & 0x7F80u) == 0x7F80u) local = 1;
  }
  if (local) atomicOr(sh, 1);
  __syncthreads();
  return *sh;
}

// Constants: b=16, c=512, t=1024, 32 groups x 16ch, 8 heads, dh=64.
#define K2SCALE 0.18033688011112042f   // 0.125 * log2(e), folded into Q
#define TSTRIDE 72                     // 36 dwords == 4 mod 32: 2-way free

// ---------------------------------------------------------------------------
// Kernel 0: weight/bias bf16 conversion only (stats moved to gn_fused).
// Vectorized float4/short4 loads. blk<768: w_qkv | <1024: w_proj |
// <1026: b_qkv | 1026: b_proj.
// ---------------------------------------------------------------------------
__global__ __launch_bounds__(256) void pre_kernel(const void* __restrict__ s1, bf16* __restrict__ d1,
                                                  const void* __restrict__ s2, bf16* __restrict__ d2,
                                                  const void* __restrict__ s3, bf16* __restrict__ d3,
                                                  const void* __restrict__ s4, bf16* __restrict__ d4,
                                                  const void* __restrict__ x) {
  const int blk = blockIdx.x;
  const int tid = threadIdx.x;
  __shared__ int fl;
  const int f32 = self_detect(x, &fl);

  const void* src; bf16* dst; int base, n;
  if (blk < 768)       { src = s1; dst = d1; base = blk;        n = 786432; }
  else if (blk < 1024) { src = s2; dst = d2; base = blk - 768;  n = 262144; }
  else if (blk < 1026) { src = s3; dst = d3; base = blk - 1024; n = 1536;   }
  else                 { src = s4; dst = d4; base = 0;          n = 512;    }
  const int i0 = (base * 256 + tid) * 4;
  if (i0 + 3 < n) {                      // full vector (always for w/b blocks)
    short4v pk;
    if (f32) {
      const float4v v = *(const float4v*)((const float*)src + i0);
#pragma unroll
      for (int j = 0; j < 4; j++) pk[j] = f2s(v[j]);
    } else {
      pk = *(const short4v*)((const bf16*)src + i0);
    }
    *(short4v*)(dst + i0) = pk;
  } else {
    for (int j = 0; j < 4; j++) {
      int i = i0 + j;
      if (i < n) dst[i] = f2b(ldin(src, i, f32));
    }
  }
}

// ---------------------------------------------------------------------------
// Kernel 1: SINGLE-PASS GroupNorm (stats + apply + transpose in one kernel).
// The old path was two-pass: stats read x (67 MB fp32) then apply re-read x
// (67 MB) + wrote xn (33 MB) = 167 MB HBM. Here each block owns (batch,
// group-pair) = 32 ch x 1024 t, holds all its 32 values/thread in REGISTERS
// (8x float4, lane-contiguous coalesced loads), reduces stats via wave-shfl
// + LDS (8 waves/group), then normalizes in-reg and writes via an LDS
// [c][t-tile] transpose -> 64 B-coalesced bf16 stores. Total 100 MB.
// Grid (16 gp, 16 b) = 256 blocks x 1024 thr = 16 waves/CU. VGPR ~50 (<=64
// forced by launch_bounds -> full residency).
// ---------------------------------------------------------------------------
__global__ __launch_bounds__(1024) void gn_fused_kernel(const void* __restrict__ x,
                                                        const void* __restrict__ gsc,
                                                        const void* __restrict__ gbi,
                                                        bf16* __restrict__ xn) {
  const int c0 = blockIdx.x * 32;        // channel base (2 groups)
  const int b  = blockIdx.y;
  const int tid = threadIdx.x;
  const int r = tid >> 5;                // ch within block 0..31
  const int q = tid & 31;                // t-quad lane 0..31

  __shared__ int fl;
  __shared__ float ws[16], wss[16], stM[2], stI[2];
  __shared__ short T[32 * 132];          // [c][t-tile 128], row stride 132
  const int f32 = self_detect(x, &fl);

  // ---- load 32 values into registers (chunk j = t-tile j, coalesced) ----
  float4v vv[8];
  const size_t rowbase = ((size_t)(b * 512 + c0 + r)) * 1024 + q * 4;
  if (f32) {
    const float* xr = (const float*)x + rowbase;
#pragma unroll
    for (int j = 0; j < 8; j++) vv[j] = *(const float4v*)(xr + j * 128);
  } else {
    const bf16* xr = (const bf16*)x + rowbase;
#pragma unroll
    for (int j = 0; j < 8; j++) {
      const short4v s4 = *(const short4v*)(xr + j * 128);
#pragma unroll
      for (int k = 0; k < 4; k++) vv[j][k] = s2f(s4[k]);
    }
  }

  // ---- stats: per-thread -> wave shfl -> per-group (waves 0-7 / 8-15) ----
  float s = 0.f, ss = 0.f;
#pragma unroll
  for (int j = 0; j < 8; j++)
#pragma unroll
    for (int k = 0; k < 4; k++) { const float f = vv[j][k]; s += f; ss += f * f; }
  for (int off = 32; off > 0; off >>= 1) {
    s  += __shfl_down(s, off);
    ss += __shfl_down(ss, off);
  }
  const int wv = tid >> 6, lane = tid & 63;
  if (lane == 0) { ws[wv] = s; wss[wv] = ss; }
  __syncthreads();
  if (tid < 2) {
    float S = 0.f, SS = 0.f;
#pragma unroll
    for (int i = 0; i < 8; i++) { S += ws[tid * 8 + i]; SS += wss[tid * 8 + i]; }
    const float mean = S * (1.f / 16384.f);
    const float var  = SS * (1.f / 16384.f) - mean * mean;
    stM[tid] = mean;
    stI[tid] = rsqrtf(var + 1e-5f);
  }
  __syncthreads();

  const int gi = r >> 4;
  const float sc = ldin(gsc, c0 + r, f32), bi = ldin(gbi, c0 + r, f32);
  const float aa = stI[gi] * sc;
  const float bb = bi - stM[gi] * stI[gi] * sc;

  // ---- apply + transpose, one 128-t tile at a time ----
  const int to = tid >> 3, c4 = (tid & 7) * 4;     // out map: (t, 4-ch chunk)
#pragma unroll
  for (int j = 0; j < 8; j++) {
    short4v pk;
#pragma unroll
    for (int k = 0; k < 4; k++) pk[k] = f2s(vv[j][k] * aa + bb);
    *(short4v*)&T[r * 132 + q * 4] = pk;           // aligned 8 B, 2-way free
    __syncthreads();
    short4v ov;
#pragma unroll
    for (int k = 0; k < 4; k++) ov[k] = T[(c4 + k) * 132 + to];
    *(short4v*)&xn[((size_t)(b * 1024 + j * 128 + to)) * 512 + c0 + c4] = ov;
    __syncthreads();
  }
}

// ---------------------------------------------------------------------------
// Kernel 2: QKV projection — 128x128 tile, 4 waves, BK=32 (R8 config).
// R9 lesson: widening to 256N shrank the grid to 768 blocks -> ~1 block/CU
// resident, latency-starved. This family wants grid DEPTH (1536 blocks,
// 6/CU queued), not arithmetic intensity.
// 1-barrier-per-iter dbuf gload16 staging; epilogue LDS-transposed.
// ---------------------------------------------------------------------------
__global__ __launch_bounds__(256) void qkv_kernel(const bf16* __restrict__ Wb,
                                                  const bf16* __restrict__ biasb,
                                                  const bf16* __restrict__ xn,
                                                  bf16* __restrict__ Qt,
                                                  bf16* __restrict__ Kt,
                                                  bf16* __restrict__ Vb) {
  const int bat = blockIdx.z;
  const int M0 = blockIdx.y * 128;       // o
  const int N0 = blockIdx.x * 128;       // t
  __shared__ short smem[18432];          // dbuf 2x(A4096|B4096)=16384 | Tt union

  const int tid = threadIdx.x;
  const int w = tid >> 6, lane = tid & 63;
  const int col = lane & 15, g = lane >> 4;
  const int wm = (w & 1) * 64, wn = (w >> 1) * 64;

  float4v acc[4][4];
#pragma unroll
  for (int i = 0; i < 4; i++)
#pragma unroll
    for (int j = 0; j < 4; j++) acc[i][j] = (float4v)(0.f);

  // staging map: tile = 128 rows x 32 k = 512 granules (16B); linear.
  int srco[2], dstb[2];
#pragma unroll
  for (int i = 0; i < 2; i++) {
    const int Gb = i * 256 + w * 64;          // wave-uniform granule base
    dstb[i] = Gb * 8;                         // LDS shorts (lane adds 16B)
    const int G = Gb + lane;
    srco[i] = (G >> 2) * 512 + (G & 3) * 8;   // row*(K=512) + col granule
  }
  const bf16* Ab  = Wb + (size_t)M0 * 512;
  const bf16* Bb2 = xn + ((size_t)bat * 1024 + N0) * 512;

  // preload k=0 into buf 0
#pragma unroll
  for (int i = 0; i < 2; i++) {
    gload16(Ab + srco[i],  &smem[dstb[i]]);
    gload16(Bb2 + srco[i], &smem[4096 + dstb[i]]);
  }
  __syncthreads();

  for (int it = 0; it < 16; ++it) {
    const int pb = it & 1;
    if (it < 15) {                       // prefetch next tile (async)
      const int kn = it * 32 + 32;
      const int nb = (1 - pb) * 8192;
#pragma unroll
      for (int i = 0; i < 2; i++) {
        gload16(Ab + kn + srco[i],  &smem[nb + dstb[i]]);
        gload16(Bb2 + kn + srco[i], &smem[nb + 4096 + dstb[i]]);
      }
    }
    const short* Ap = &smem[pb * 8192];
    const short* Bp = Ap + 4096;
    short8 af[4], bf4[4];
#pragma unroll
    for (int mt = 0; mt < 4; mt++) af[mt] = *(const short8*)&Ap[(wm + mt * 16 + col) * 32 + g * 8];
#pragma unroll
    for (int nt = 0; nt < 4; nt++) bf4[nt] = *(const short8*)&Bp[(wn + nt * 16 + col) * 32 + g * 8];
#pragma unroll
    for (int mt = 0; mt < 4; mt++)
#pragma unroll
      for (int nt = 0; nt < 4; nt++) acc[mt][nt] = mfma16(af[mt], bf4[nt], acc[mt][nt]);
    __syncthreads();                     // reads done + next DMA drained at use
  }

  // ---- epilogue ----
  const int sec = (M0 + wm) >> 6;
  const int h = sec / 3, kind = sec % 3; // 0=Q 1=K 2=V
  const size_t bh = (size_t)bat * 8 + h;
  const float qs = (kind == 0) ? K2SCALE : 1.f;
  short* Tw = smem + w * 4608;

  float bv[4][4];
#pragma unroll
  for (int mt = 0; mt < 4; mt++)
#pragma unroll
    for (int r = 0; r < 4; r++) bv[mt][r] = b2f(biasb[M0 + wm + mt * 16 + g * 4 + r]);

  if (kind == 2) {                       // V -> [c][t]
#pragma unroll
    for (int mt = 0; mt < 4; mt++)
#pragma unroll
      for (int nt = 0; nt < 4; nt++)
#pragma unroll
        for (int r = 0; r < 4; r++) {
          const int lo = mt * 16 + g * 4 + r;
          const int lt = nt * 16 + col;
          Tw[lo * TSTRIDE + lt] = f2s(acc[mt][nt][r] + bv[mt][r]);
        }
#pragma unroll
    for (int j = 0; j < 8; j++) {
      const int lo = j * 8 + (lane >> 3);
      const int gr = lane & 7;
      short8 v = *(const short8*)&Tw[lo * TSTRIDE + gr * 8];
      *(short8*)(Vb + (bh * 64 + lo) * 1024 + N0 + wn + gr * 8) = v;
    }
  } else {                               // Q/K -> [t][c]
#pragma unroll
    for (int mt = 0; mt < 4; mt++)
#pragma unroll
      for (int nt = 0; nt < 4; nt++) {
        short4v pk;
#pragma unroll
        for (int r = 0; r < 4; r++) pk[r] = f2s((acc[mt][nt][r] + bv[mt][r]) * qs);
        *(short4v*)&Tw[(nt * 16 + col) * TSTRIDE + mt * 16 + g * 4] = pk;
      }
    bf16* dst = (kind == 0) ? Qt : Kt;
#pragma unroll
    for (int j = 0; j < 8; j++) {
      const int tl = j * 8 + (lane >> 3), c8 = (lane & 7) * 8;
      short8 v = *(const short8*)&Tw[tl * TSTRIDE + c8];
      *(short8*)(dst + (bh * 1024 + N0 + wn + tl) * 64 + c8) = v;
    }
  }
}

// ---------------------------------------------------------------------------
// Kernel 3: flash attention — R3 core (plateau of this family per R4-R7
// ablations) + S-init via persistent zero-register C operand (R10: 45.4 ->
// 44.3, MfmaUtil 29 -> 31). QBLK=64/wave, KVBLK=64, dbuf K/V (32KB),
// 1 barrier/iter, grid (128,4). Fragment-major LDS (conflict-free via
// per-lane global src permute), T12 in-reg P (cvt_pk + permlane32_swap),
// raw exp2.
// ---------------------------------------------------------------------------
__global__ __launch_bounds__(256, 2) void attn_kernel(const bf16* __restrict__ Qt,
                                                      const bf16* __restrict__ Kt,
                                                      const bf16* __restrict__ Vb,
                                                      bf16* __restrict__ xattn) {
  const int bh = blockIdx.x;             // XCD affinity dim
  const int t0 = blockIdx.y * 256;
  const int b = bh >> 3, h = bh & 7;
  const int tid = threadIdx.x;
  const int w = tid >> 6, lane = tid & 63;
  const int qv = lane & 31, hh = lane >> 5;
  const int q0 = t0 + w * 64;

  __shared__ short Ks[8192];             // 16 KB: dbuf 2 x 4096 shorts
  __shared__ short Vs[8192];             // 16 KB

  const bf16* kbase = Kt + (size_t)bh * 65536;   // [t][c]
  const bf16* vbase = Vb + (size_t)bh * 65536;   // [c][t]

  // staging: granule G = w*128 + i*64 + lane -> (a,ks,qvs,hhs)
  int ksrc[2], vsrc[2];
  const int ldst0 = w * 1024, ldst1 = w * 1024 + 512;   // shorts in buffer
#pragma unroll
  for (int i = 0; i < 2; i++) {
    const int G = w * 128 + i * 64 + lane;
    const int a = G >> 8, ks = (G >> 6) & 3, qvs = (G >> 1) & 31, hhs = G & 1;
    const int co = (ks * 2 + hhs) * 8;          // channel offset (shorts)
    ksrc[i] = (a * 32 + qvs) * 64 + co;         // K row stride 64
    vsrc[i] = (a * 32 + qvs) * 1024 + co;       // V row stride 1024
  }
  const int rb = (qv * 2 + hh) * 8;             // lane-const read offset

  // Q frags (B-operand): lane q=qv, k = 16*ks + 8*hh + i. 32 VGPRs.
  short8 qb[2][4];
#pragma unroll
  for (int qt = 0; qt < 2; qt++)
#pragma unroll
    for (int ks = 0; ks < 4; ks++)
      qb[qt][ks] = ld8(Qt + ((size_t)bh * 1024 + q0 + qt * 32 + qv) * 64 + ks * 16 + hh * 8);

  f32x16 O[2][2];                        // [q-tile][c-half]
#pragma unroll
  for (int qt = 0; qt < 2; qt++)
#pragma unroll
    for (int o = 0; o < 2; o++) O[qt][o] = (f32x16)(0.f);
  float l[2] = {0.f, 0.f};
  short8 pa[2][4];                       // P A-frags per q-tile
  const f32x16 FZ = (f32x16)(0.f);       // persistent zero C-operand

  // preload tile 0 into buf 0
  gload16(kbase + ksrc[0], &Ks[ldst0]);
  gload16(kbase + ksrc[1], &Ks[ldst1]);
  gload16(vbase + vsrc[0], &Vs[ldst0]);
  gload16(vbase + vsrc[1], &Vs[ldst1]);
  __syncthreads();

// exp2 + row-sum + pack S (kv tile a) into pa[qt][2a], pa[qt][2a+1]
#define SMAX(S, qt, a)                                                          \
  {                                                                             \
    _Pragma("unroll")                                                           \
    for (int j = 0; j < 16; j++) S[j] = __builtin_amdgcn_exp2f(S[j]);           \
    l[qt] += (((S[0] + S[1]) + (S[2] + S[3])) + ((S[4] + S[5]) + (S[6] + S[7])))\
       + (((S[8] + S[9]) + (S[10] + S[11])) + ((S[12] + S[13]) + (S[14] + S[15]))); \
    _Pragma("unroll")                                                           \
    for (int kp = 0; kp < 2; kp++) {                                            \
      int X  = cvtpk(S[8 * kp + 0], S[8 * kp + 1]);                             \
      int Y  = cvtpk(S[8 * kp + 4], S[8 * kp + 5]);                             \
      int X2 = cvtpk(S[8 * kp + 2], S[8 * kp + 3]);                             \
      int Y2 = cvtpk(S[8 * kp + 6], S[8 * kp + 7]);                             \
      plswap(X, Y);                                                             \
      plswap(X2, Y2);                                                           \
      const int4v wv = {X, X2, Y, Y2};                                          \
      pa[qt][(a) * 2 + kp] = __builtin_bit_cast(short8, wv);                    \
    }                                                                           \
  }

#pragma unroll 2
  for (int it = 0; it < 16; ++it) {
    const int cur = (it & 1) * 4096;
    const int nxt = 4096 - cur;
    // ---- issue DMA for tile it+1 into the other buffer ----
    if (it < 15) {
      gload16(kbase + (it + 1) * 4096 + ksrc[0], &Ks[nxt + ldst0]);
      gload16(kbase + (it + 1) * 4096 + ksrc[1], &Ks[nxt + ldst1]);
      gload16(vbase + (it + 1) * 64 + vsrc[0],   &Vs[nxt + ldst0]);
      gload16(vbase + (it + 1) * 64 + vsrc[1],   &Vs[nxt + ldst1]);
    }
    // ---- QK + softmax (kf shared across both q-tiles) ----
#pragma unroll
    for (int a = 0; a < 2; a++) {
      short8 kf[4];
#pragma unroll
      for (int ks = 0; ks < 4; ks++)
        kf[ks] = *(const short8*)&Ks[cur + (a * 4 + ks) * 512 + rb];
#pragma unroll
      for (int qt = 0; qt < 2; qt++) {
        f32x16 S = mfma32(kf[0], qb[qt][0], FZ);   // init via MFMA (D != C)
#pragma unroll
        for (int ks = 1; ks < 4; ks++) S = mfma32(kf[ks], qb[qt][ks], S);
        SMAX(S, qt, a);
      }
    }
    // ---- PV (vf shared across both q-tiles) ----
#pragma unroll
    for (int o = 0; o < 2; o++) {
      short8 vf[4];
#pragma unroll
      for (int ks = 0; ks < 4; ks++)
        vf[ks] = *(const short8*)&Vs[cur + (o * 4 + ks) * 512 + rb];
#pragma unroll
      for (int qt = 0; qt < 2; qt++)
#pragma unroll
        for (int ks = 0; ks < 4; ks++)
          O[qt][o] = mfma32(pa[qt][ks], vf[ks], O[qt][o]);
    }
    __syncthreads();                     // reads done; next-buf DMA drained
  }
#undef SMAX

  // ---- epilogue: cross-half row-sum, normalize, direct stores ----
#pragma unroll
  for (int qt = 0; qt < 2; qt++) {
    float lt = l[qt] + __shfl_xor(l[qt], 32);
    const float inv = 1.f / lt;
    float* lf = (float*)Ks + w * 64 + qt * 32;  // Ks dead; disjoint per wave
    lf[qv] = inv;                               // both halves write same value

    bf16* ob = xattn + ((size_t)b * 1024 + q0 + qt * 32 + 4 * hh) * 512 + h * 64 + qv;
#pragma unroll
    for (int r = 0; r < 16; r++) {
      const int qoff = (r & 3) + 8 * (r >> 2);
      const float iv = lf[qoff + 4 * hh];       // same addr across half
      ob[(size_t)qoff * 512]      = f2b(O[qt][0][r] * iv);
      ob[(size_t)qoff * 512 + 32] = f2b(O[qt][1][r] * iv);
    }
  }
}

// ---------------------------------------------------------------------------
// Kernel 4: proj GEMM, same BK=32 dbuf one-barrier staging.
// out = Wp*xattn + bias + x; epilogue transposed, full-line stores.
// Residual loads vectorized (float4 x2 / short8). Dtype via self_detect
// (res == x, so the 16 KB probe is data this kernel reads anyway).
// ---------------------------------------------------------------------------
__global__ __launch_bounds__(256) void proj_kernel(const bf16* __restrict__ Wp,
                                                   const bf16* __restrict__ biasb,
                                                   const bf16* __restrict__ xattn,
                                                   const void* __restrict__ res,
                                                   void* __restrict__ out) {
  const int bat = blockIdx.z;
  const int M0 = blockIdx.y * 128;
  const int N0 = blockIdx.x * 128;
  __shared__ short smem[18432];
  __shared__ int fl;
  const int f32 = self_detect(res, &fl);

  const int tid = threadIdx.x;
  const int w = tid >> 6, lane = tid & 63;
  const int col = lane & 15, g = lane >> 4;
  const int wm = (w & 1) * 64, wn = (w >> 1) * 64;

  float4v acc[4][4];
#pragma unroll
  for (int i = 0; i < 4; i++)
#pragma unroll
    for (int j = 0; j < 4; j++) acc[i][j] = (float4v)(0.f);

  int srco[2], dstb[2];
#pragma unroll
  for (int i = 0; i < 2; i++) {
    const int Gb = i * 256 + w * 64;
    dstb[i] = Gb * 8;
    const int G = Gb + lane;
    srco[i] = (G >> 2) * 512 + (G & 3) * 8;
  }
  const bf16* Ab  = Wp + (size_t)M0 * 512;
  const bf16* Bb2 = xattn + ((size_t)bat * 1024 + N0) * 512;

#pragma unroll
  for (int i = 0; i < 2; i++) {
    gload16(Ab + srco[i],  &smem[dstb[i]]);
    gload16(Bb2 + srco[i], &smem[4096 + dstb[i]]);
  }
  __syncthreads();

  for (int it = 0; it < 16; ++it) {
    const int pb = it & 1;
    if (it < 15) {
      const int kn = it * 32 + 32;
      const int nb = (1 - pb) * 8192;
#pragma unroll
      for (int i = 0; i < 2; i++) {
        gload16(Ab + kn + srco[i],  &smem[nb + dstb[i]]);
        gload16(Bb2 + kn + srco[i], &smem[nb + 4096 + dstb[i]]);
      }
    }
    const short* Ap = &smem[pb * 8192];
    const short* Bp = Ap + 4096;
    short8 af[4], bf4[4];
#pragma unroll
    for (int mt = 0; mt < 4; mt++) af[mt] = *(const short8*)&Ap[(wm + mt * 16 + col) * 32 + g * 8];
#pragma unroll
    for (int nt = 0; nt < 4; nt++) bf4[nt] = *(const short8*)&Bp[(wn + nt * 16 + col) * 32 + g * 8];
#pragma unroll
    for (int mt = 0; mt < 4; mt++)
#pragma unroll
      for (int nt = 0; nt < 4; nt++) acc[mt][nt] = mfma16(af[mt], bf4[nt], acc[mt][nt]);
    __syncthreads();
  }

  short* Tw = smem + w * 4608;
  float bv[4][4];
#pragma unroll
  for (int mt = 0; mt < 4; mt++)
#pragma unroll
    for (int r = 0; r < 4; r++) bv[mt][r] = b2f(biasb[M0 + wm + mt * 16 + g * 4 + r]);

#pragma unroll
  for (int mt = 0; mt < 4; mt++)
#pragma unroll
    for (int nt = 0; nt < 4; nt++)
#pragma unroll
      for (int r = 0; r < 4; r++) {
        const int lo = mt * 16 + g * 4 + r;
        const int lt = nt * 16 + col;
        Tw[lo * TSTRIDE + lt] = f2s(acc[mt][nt][r] + bv[mt][r]);
      }
#pragma unroll
  for (int j = 0; j < 8; j++) {
    const int lo = j * 8 + (lane >> 3);
    const int gr = lane & 7;
    short8 v = *(const short8*)&Tw[lo * TSTRIDE + gr * 8];
    const int o = M0 + wm + lo;
    const size_t ci = ((size_t)bat * 512 + o) * 1024 + N0 + wn + gr * 8;
    if (f32) {
      const float4v r0 = *(const float4v*)((const float*)res + ci);
      const float4v r1 = *(const float4v*)((const float*)res + ci + 4);
      float4v o0, o1;
#pragma unroll
      for (int e = 0; e < 4; e++) o0[e] = s2f(v[e]) + r0[e];
#pragma unroll
      for (int e = 0; e < 4; e++) o1[e] = s2f(v[e + 4]) + r1[e];
      *(float4v*)((float*)out + ci) = o0;
      *(float4v*)((float*)out + ci + 4) = o1;
    } else {
      const short8 rv = *(const short8*)((const bf16*)res + ci);
      short8 ov;
#pragma unroll
      for (int e = 0; e < 8; e++)
        ov[e] = f2s(s2f(v[e]) + s2f(rv[e]));
      *(short8*)((bf16*)out + ci) = ov;
    }
  }
}

// ---------------------------------------------------------------------------
extern "C" void kernel_launch(void* const* d_in, const int* in_sizes, int n_in,
                              void* d_out, int out_size, void* d_ws, size_t ws_size,
                              hipStream_t stream) {
  const void* x      = d_in[0];
  const void* gsc    = d_in[1];
  const void* gbi    = d_in[2];
  const void* w_qkv  = d_in[3];
  const void* b_qkv  = d_in[4];
  const void* w_proj = d_in[5];
  const void* b_proj = d_in[6];

  char* p = (char*)d_ws;
  bf16*   xn    = (bf16*)p;                p += (size_t)16 * 1024 * 512 * 2;
  bf16*   Qt    = (bf16*)p;                p += (size_t)128 * 1024 * 64 * 2;
  bf16*   Kt    = (bf16*)p;                p += (size_t)128 * 1024 * 64 * 2;
  bf16*   Vb    = (bf16*)p;                p += (size_t)128 * 64 * 1024 * 2;
  bf16*   Wqb   = (bf16*)p;                p += (size_t)1536 * 512 * 2;
  bf16*   Wpb   = (bf16*)p;                p += (size_t)512 * 512 * 2;
  bf16*   Bqb   = (bf16*)p;                p += (size_t)1536 * 2;
  bf16*   Bpb   = (bf16*)p;                p += (size_t)512 * 2;
  bf16*   xattn = (bf16*)p;

  pre_kernel<<<1027, 256, 0, stream>>>(w_qkv, Wqb, w_proj, Wpb,
                                       b_qkv, Bqb, b_proj, Bpb, x);
  gn_fused_kernel<<<dim3(16, 16), 1024, 0, stream>>>(x, gsc, gbi, xn);
  qkv_kernel<<<dim3(8, 12, 16), 256, 0, stream>>>(Wqb, Bqb, xn, Qt, Kt, Vb);
  attn_kernel<<<dim3(128, 4), 256, 0, stream>>>(Qt, Kt, Vb, xattn);
  proj_kernel<<<dim3(8, 4, 16), 256, 0, stream>>>(Wpb, Bpb, xattn, x, d_out);
}